// Round 1
// baseline (351.124 us; speedup 1.0000x reference)
//
#include <hip/hip_runtime.h>
#include <hip/hip_bf16.h>

// Problem constants (from setup_inputs)
#define Bb 8
#define Tt 20
#define Nn 16
#define Cc 1024
#define ROWS (Bb * Tt * Nn)   // 2560
#define K2 9

static __device__ __forceinline__ unsigned short f2bf(float f) {
    unsigned int u = __builtin_bit_cast(unsigned int, f);
    unsigned int lsb = (u >> 16) & 1u;
    u += 0x7fffu + lsb;                 // round-to-nearest-even
    return (unsigned short)(u >> 16);
}

// ---------------------------------------------------------------------------
// Kernel 0: convert W_hidden (fp32 [C][C]) -> bf16 [C][C]
// ---------------------------------------------------------------------------
__global__ __launch_bounds__(256) void convw_kernel(const float* __restrict__ W,
                                                    unsigned short* __restrict__ Wb) {
    int idx = (blockIdx.x * 256 + threadIdx.x) * 4;
    float4 v = *(const float4*)(W + idx);
    ushort4 o;
    o.x = f2bf(v.x); o.y = f2bf(v.y); o.z = f2bf(v.z); o.w = f2bf(v.w);
    *(ushort4*)(Wb + idx) = o;
}

// ---------------------------------------------------------------------------
// Kernel 1: offset conv.  off[row][0..17] = b[o] + sum_{c,kh,kw} w[o,c,kh,kw] *
//           pf[b, t+(kh-1)*R, n+(kw-1)*R, c]   (zero outside bounds)
// One block = 4 consecutive rows (same b,t; n0..n0+3). 256 threads over channels.
// ---------------------------------------------------------------------------
template <int RATIO>
__global__ __launch_bounds__(256) void offs_kernel(const float* __restrict__ pf,
                                                   const float* __restrict__ w,
                                                   const float* __restrict__ bias,
                                                   float* __restrict__ off) {
    const int r0 = blockIdx.x * 4;
    const int b  = r0 / (Tt * Nn);
    const int t  = (r0 / Nn) % Tt;
    const int n0 = r0 % Nn;
    const int tid = threadIdx.x;

    // uniform per-(tap,row) base offsets; -1 marks out-of-bounds (zero pad)
    int bas[9][4];
#pragma unroll
    for (int tap = 0; tap < 9; ++tap) {
        const int tt = t + (tap / 3 - 1) * RATIO;
        const bool okt = (tt >= 0) && (tt < Tt);
#pragma unroll
        for (int j = 0; j < 4; ++j) {
            const int nn = n0 + j + (tap % 3 - 1) * RATIO;
            bas[tap][j] = (okt && nn >= 0 && nn < Nn)
                              ? ((b * Tt + tt) * Nn + nn) * Cc
                              : -1;
        }
    }

    float acc[4][18];
#pragma unroll
    for (int j = 0; j < 4; ++j)
#pragma unroll
        for (int o = 0; o < 18; ++o) acc[j][o] = 0.f;

    for (int ci = 0; ci < 4; ++ci) {
        const int c = tid + ci * 256;
        float v[9][4];
#pragma unroll
        for (int tap = 0; tap < 9; ++tap)
#pragma unroll
            for (int j = 0; j < 4; ++j)
                v[tap][j] = (bas[tap][j] >= 0) ? pf[bas[tap][j] + c] : 0.f;

#pragma unroll
        for (int o = 0; o < 18; ++o) {
            const float* wp = w + ((size_t)o * Cc + c) * 9;
            float w9[9];
#pragma unroll
            for (int tap = 0; tap < 9; ++tap) w9[tap] = wp[tap];
#pragma unroll
            for (int tap = 0; tap < 9; ++tap)
#pragma unroll
                for (int j = 0; j < 4; ++j)
                    acc[j][o] = fmaf(v[tap][j], w9[tap], acc[j][o]);
        }
    }

    // reduce 256 threads -> 18 outputs per row
    const int lane = tid & 63, wv = tid >> 6;
    __shared__ float red[4][4][18];
#pragma unroll
    for (int j = 0; j < 4; ++j)
#pragma unroll
        for (int o = 0; o < 18; ++o) {
            float s = acc[j][o];
            s += __shfl_down(s, 32); s += __shfl_down(s, 16); s += __shfl_down(s, 8);
            s += __shfl_down(s, 4);  s += __shfl_down(s, 2);  s += __shfl_down(s, 1);
            if (lane == 0) red[wv][j][o] = s;
        }
    __syncthreads();
    if (tid < 72) {
        const int j = tid / 18, o = tid % 18;
        off[(size_t)(r0 + j) * 18 + o] =
            red[0][j][o] + red[1][j][o] + red[2][j][o] + red[3][j][o] + bias[o];
    }
}

// ---------------------------------------------------------------------------
// Kernel 2: deformable bilinear gather.
// One block per row (b,t,n); 256 threads over channels (4 each).
// RATIO==1: ftsum[row][c]  = sum_k ft_infer
// RATIO==2: Ab[row][c]     = bf16((ftsum + sum_k)/18); mad[row][k][c] = ft_infer
// ---------------------------------------------------------------------------
template <int RATIO, bool FINAL>
__global__ __launch_bounds__(256) void gather_kernel(const float* __restrict__ pf,
                                                     const float* __restrict__ off,
                                                     float* __restrict__ ftsum,
                                                     unsigned short* __restrict__ Ab,
                                                     float* __restrict__ mad) {
    const int row = blockIdx.x;
    const int b = row / (Tt * Nn);
    const int t = (row / Nn) % Tt;
    const int n = row % Nn;
    const int tid = threadIdx.x;

    __shared__ float so[18];
    if (tid < 18) so[tid] = off[(size_t)row * 18 + tid];
    __syncthreads();

    const float tmax = (float)(Tt + 2 * RATIO - 1);
    const float nmax = (float)(Nn + 2 * RATIO - 1);

    float acc[4] = {0.f, 0.f, 0.f, 0.f};

#pragma unroll
    for (int k = 0; k < 9; ++k) {
        const float gt = (float)((k / 3 - 1) * RATIO);
        const float gn = (float)((k % 3 - 1) * RATIO);
        const float pos_t = (float)(t + RATIO) + gt + so[k];
        const float pos_n = (float)(n + RATIO) + gn + so[9 + k];

        const float fl_t = floorf(pos_t), fl_n = floorf(pos_n);
        const float l_t = fminf(fmaxf(fl_t, 0.f), tmax);
        const float r_t = fminf(fmaxf(fl_t + 1.f, 0.f), tmax);
        const float l_n = fminf(fmaxf(fl_n, 0.f), nmax);
        const float r_n = fminf(fmaxf(fl_n + 1.f, 0.f), nmax);
        const float pt_ = fminf(fmaxf(pos_t, 0.f), tmax);
        const float pn_ = fminf(fmaxf(pos_n, 0.f), nmax);

        const float wtl = 1.f - fabsf(pt_ - l_t);   // weight along t for l_t
        const float wtr = 1.f - fabsf(pt_ - r_t);
        const float wnl = 1.f - fabsf(pn_ - l_n);
        const float wnr = 1.f - fabsf(pn_ - r_n);

        const float clt = wtl * wnl;   // (l_t, l_n)
        const float crb = wtr * wnr;   // (r_t, r_n)
        const float clb = wtr * wnl;   // (r_t, l_n)
        const float crt = wtl * wnr;   // (l_t, r_n)

        // original-coordinate indices (subtract pad = RATIO)
        const int ilt = (int)l_t - RATIO, irt = (int)r_t - RATIO;
        const int iln = (int)l_n - RATIO, irn = (int)r_n - RATIO;
        const bool vtl = (unsigned)ilt < (unsigned)Tt;
        const bool vtr = (unsigned)irt < (unsigned)Tt;
        const bool vnl = (unsigned)iln < (unsigned)Nn;
        const bool vnr = (unsigned)irn < (unsigned)Nn;

        const size_t base_b = (size_t)b * Tt * Nn * Cc;
        const size_t o_lt = base_b + ((size_t)ilt * Nn + iln) * Cc;
        const size_t o_rb = base_b + ((size_t)irt * Nn + irn) * Cc;
        const size_t o_lb = base_b + ((size_t)irt * Nn + iln) * Cc;
        const size_t o_rt = base_b + ((size_t)ilt * Nn + irn) * Cc;
        const bool g_lt = vtl && vnl, g_rb = vtr && vnr;
        const bool g_lb = vtr && vnl, g_rt = vtl && vnr;

#pragma unroll
        for (int ci = 0; ci < 4; ++ci) {
            const int c = tid + ci * 256;
            const float s_lt = g_lt ? pf[o_lt + c] : 0.f;
            const float s_rb = g_rb ? pf[o_rb + c] : 0.f;
            const float s_lb = g_lb ? pf[o_lb + c] : 0.f;
            const float s_rt = g_rt ? pf[o_rt + c] : 0.f;
            const float val = clt * s_lt + crb * s_rb + clb * s_lb + crt * s_rt;
            acc[ci] += val;
            if (FINAL) mad[((size_t)row * 9 + k) * Cc + c] = val;
        }
    }

#pragma unroll
    for (int ci = 0; ci < 4; ++ci) {
        const int c = tid + ci * 256;
        if (FINAL) {
            const float f = (ftsum[(size_t)row * Cc + c] + acc[ci]) * (1.f / 18.f);
            Ab[(size_t)row * Cc + c] = f2bf(f);
        } else {
            ftsum[(size_t)row * Cc + c] = acc[ci];
        }
    }
}

// ---------------------------------------------------------------------------
// Kernel 3: bf16 MFMA GEMM  C[M][N] = A[M][K] * B[N][K]^T  (both K-major)
// 128x128 tile, BK=32, 4 waves each computing 64x64 (4x4 of 16x16x32 frags).
// global_load_lds width-16 staging with XOR-4 chunk swizzle.
// ---------------------------------------------------------------------------
typedef __attribute__((ext_vector_type(8))) short short8;
typedef __attribute__((ext_vector_type(4))) float floatx4;
typedef __attribute__((address_space(1))) const unsigned int guint;
typedef __attribute__((address_space(3))) unsigned int luint;

__global__ __launch_bounds__(256) void gemm_bt_kernel(const unsigned short* __restrict__ A,
                                                      const unsigned short* __restrict__ Bw,
                                                      float* __restrict__ C,
                                                      int M, int N, int K) {
    __shared__ unsigned short As[128 * 32];
    __shared__ unsigned short Bs[128 * 32];

    const int tid  = threadIdx.x;
    const int lane = tid & 63;
    const int wave = tid >> 6;
    const int quad = lane >> 4;
    const int l15  = lane & 15;
    const int row0 = blockIdx.x * 128;
    const int col0 = blockIdx.y * 128;
    const int wm = (wave >> 1) * 64;
    const int wn = (wave & 1) * 64;

    floatx4 acc[4][4];
#pragma unroll
    for (int i = 0; i < 4; ++i)
#pragma unroll
        for (int j = 0; j < 4; ++j) acc[i][j] = (floatx4){0.f, 0.f, 0.f, 0.f};

    // staging decode: chunk cc covers LDS bytes [cc*16, cc*16+16); holds
    // row m=cc>>2, global k-chunk (cc&3)^(m&3)  (XOR swizzle vs bank conflicts)
    const int cc0 = tid,      m0 = cc0 >> 2, kq0 = (cc0 & 3) ^ (m0 & 3);
    const int cc1 = tid + 256, m1 = cc1 >> 2, kq1 = (cc1 & 3) ^ (m1 & 3);
    const unsigned short* gA0 = A  + (size_t)(row0 + m0) * K + kq0 * 8;
    const unsigned short* gA1 = A  + (size_t)(row0 + m1) * K + kq1 * 8;
    const unsigned short* gB0 = Bw + (size_t)(col0 + m0) * K + kq0 * 8;
    const unsigned short* gB1 = Bw + (size_t)(col0 + m1) * K + kq1 * 8;
    unsigned short* lA0 = As + wave * 512;           // ushort units (1024B/wave)
    unsigned short* lA1 = As + 2048 + wave * 512;
    unsigned short* lB0 = Bs + wave * 512;
    unsigned short* lB1 = Bs + 2048 + wave * 512;

    for (int kt = 0; kt < K; kt += 32) {
        __builtin_amdgcn_global_load_lds((guint*)(const void*)(gA0 + kt), (luint*)(void*)lA0, 16, 0, 0);
        __builtin_amdgcn_global_load_lds((guint*)(const void*)(gA1 + kt), (luint*)(void*)lA1, 16, 0, 0);
        __builtin_amdgcn_global_load_lds((guint*)(const void*)(gB0 + kt), (luint*)(void*)lB0, 16, 0, 0);
        __builtin_amdgcn_global_load_lds((guint*)(const void*)(gB1 + kt), (luint*)(void*)lB1, 16, 0, 0);
        __syncthreads();

        short8 af[4], bf[4];
#pragma unroll
        for (int i = 0; i < 4; ++i) {
            const int m = wm + i * 16 + l15;
            af[i] = *(const short8*)&As[m * 32 + ((quad ^ (m & 3)) << 3)];
            const int n = wn + i * 16 + l15;
            bf[i] = *(const short8*)&Bs[n * 32 + ((quad ^ (n & 3)) << 3)];
        }
#pragma unroll
        for (int i = 0; i < 4; ++i)
#pragma unroll
            for (int j = 0; j < 4; ++j)
                acc[i][j] = __builtin_amdgcn_mfma_f32_16x16x32_bf16(af[i], bf[j], acc[i][j], 0, 0, 0);
        __syncthreads();
    }

#pragma unroll
    for (int i = 0; i < 4; ++i)
#pragma unroll
        for (int j = 0; j < 4; ++j)
#pragma unroll
            for (int r = 0; r < 4; ++r) {
                const int row = row0 + wm + i * 16 + quad * 4 + r;
                const int col = col0 + wn + j * 16 + l15;
                C[(size_t)row * N + col] = acc[i][j][r];
            }
}

// ---------------------------------------------------------------------------
extern "C" void kernel_launch(void* const* d_in, const int* in_sizes, int n_in,
                              void* d_out, int out_size, void* d_ws, size_t ws_size,
                              hipStream_t stream) {
    const float* pf = (const float*)d_in[0];   // [B,T,N,C]
    const float* Wh = (const float*)d_in[1];   // [C,C]
    const float* w1 = (const float*)d_in[2];   // [18,C,3,3]
    const float* b1 = (const float*)d_in[3];   // [18]
    const float* w2 = (const float*)d_in[4];
    const float* b2 = (const float*)d_in[5];

    float* dyn = (float*)d_out;                    // [ROWS][C]
    float* mad = dyn + (size_t)ROWS * Cc;          // [ROWS][9][C]

    // workspace layout (≈18.2 MB)
    float* off1  = (float*)d_ws;                                 // ROWS*18
    float* off2  = off1 + (size_t)ROWS * 18;                     // ROWS*18
    float* ftsum = off2 + (size_t)ROWS * 18;                     // ROWS*C
    unsigned short* Ab = (unsigned short*)(ftsum + (size_t)ROWS * Cc);  // ROWS*C bf16
    unsigned short* Wb = Ab + (size_t)ROWS * Cc;                 // C*C bf16

    convw_kernel<<<(Cc * Cc) / (256 * 4), 256, 0, stream>>>(Wh, Wb);
    offs_kernel<1><<<ROWS / 4, 256, 0, stream>>>(pf, w1, b1, off1);
    offs_kernel<2><<<ROWS / 4, 256, 0, stream>>>(pf, w2, b2, off2);
    gather_kernel<1, false><<<ROWS, 256, 0, stream>>>(pf, off1, ftsum, nullptr, nullptr);
    gather_kernel<2, true><<<ROWS, 256, 0, stream>>>(pf, off2, ftsum, Ab, mad);
    gemm_bt_kernel<<<dim3(20, 8), 256, 0, stream>>>(Ab, Wb, dyn, ROWS, Cc, Cc);
}

// Round 2
// 245.531 us; speedup vs baseline: 1.4301x; 1.4301x over previous
//
#include <hip/hip_runtime.h>
#include <hip/hip_bf16.h>

// Problem constants (from setup_inputs)
#define Bb 8
#define Tt 20
#define Nn 16
#define Cc 1024
#define ROWS (Bb * Tt * Nn)   // 2560
#define K2 9

typedef __attribute__((ext_vector_type(8))) short short8;
typedef __attribute__((ext_vector_type(8))) _Float16 half8;
typedef __attribute__((ext_vector_type(4))) _Float16 half4;
typedef __attribute__((ext_vector_type(4))) float floatx4;
typedef __attribute__((address_space(1))) const unsigned int guint;
typedef __attribute__((address_space(3))) unsigned int luint;

static __device__ __forceinline__ unsigned short f2bf(float f) {
    unsigned int u = __builtin_bit_cast(unsigned int, f);
    unsigned int lsb = (u >> 16) & 1u;
    u += 0x7fffu + lsb;                 // round-to-nearest-even
    return (unsigned short)(u >> 16);
}

// ---------------------------------------------------------------------------
// Kernel 0: convert W_hidden (fp32 [C][C]) -> bf16 [C][C]
// ---------------------------------------------------------------------------
__global__ __launch_bounds__(256) void convw_kernel(const float* __restrict__ W,
                                                    unsigned short* __restrict__ Wb) {
    int idx = (blockIdx.x * 256 + threadIdx.x) * 4;
    float4 v = *(const float4*)(W + idx);
    ushort4 o;
    o.x = f2bf(v.x); o.y = f2bf(v.y); o.z = f2bf(v.z); o.w = f2bf(v.w);
    *(ushort4*)(Wb + idx) = o;
}

// ---------------------------------------------------------------------------
// Kernel 0b: x fp32 -> fp16  (A operand of the offset GEMM)
// ---------------------------------------------------------------------------
__global__ __launch_bounds__(256) void convxh_kernel(const float* __restrict__ x,
                                                     _Float16* __restrict__ xh) {
    int idx = (blockIdx.x * 256 + threadIdx.x) * 4;
    float4 v = *(const float4*)(x + idx);
    half4 o;
    o.x = (_Float16)v.x; o.y = (_Float16)v.y; o.z = (_Float16)v.z; o.w = (_Float16)v.w;
    *(half4*)(xh + idx) = o;
}

// ---------------------------------------------------------------------------
// Kernel 0c: conv weights [18][C][3][3] fp32 -> [tap][32][C] fp16, o padded
//            to 32 with zeros. Both ratios.
// ---------------------------------------------------------------------------
__global__ __launch_bounds__(256) void convwh_kernel(const float* __restrict__ w1,
                                                     const float* __restrict__ w2,
                                                     _Float16* __restrict__ wh1,
                                                     _Float16* __restrict__ wh2) {
    int idx = blockIdx.x * 256 + threadIdx.x;       // 9*32*1024 total
    int c = idx & 1023;
    int o = (idx >> 10) & 31;
    int tap = idx >> 15;
    float v1 = 0.f, v2 = 0.f;
    if (o < 18) {
        size_t src = ((size_t)o * Cc + c) * 9 + tap;
        v1 = w1[src]; v2 = w2[src];
    }
    wh1[idx] = (_Float16)v1;
    wh2[idx] = (_Float16)v2;
}

// ---------------------------------------------------------------------------
// Kernel 0d: init off1/off2 with bias, zero the zero-page (ws is poisoned).
// ---------------------------------------------------------------------------
__global__ __launch_bounds__(256) void init_kernel(const float* __restrict__ b1,
                                                   const float* __restrict__ b2,
                                                   float* __restrict__ off1,
                                                   float* __restrict__ off2,
                                                   _Float16* __restrict__ zp) {
    int idx = blockIdx.x * 256 + threadIdx.x;
    if (idx < Cc) zp[idx] = (_Float16)0.f;
    if (idx < ROWS * 18) {
        int o = idx % 18;
        off1[idx] = b1[o];
        off2[idx] = b2[o];
    }
}

// ---------------------------------------------------------------------------
// Kernel 1: offset conv as split-K MFMA GEMM.
// Grid (80 M-tiles of 32 rows, 9 taps). Block 256 thr = 4 waves, each wave one
// 16x16 tile of the 32x32 output. K=1024 (channels); A = x rows shifted by the
// tap (zero page if OOB), B = wh[tap] ([32][1024] fp16, K-major).
// Partial sums accumulate into off via fp32 atomicAdd (bias pre-loaded).
// ---------------------------------------------------------------------------
template <int RATIO>
__global__ __launch_bounds__(256) void offs_mfma_kernel(const _Float16* __restrict__ xh,
                                                        const _Float16* __restrict__ wh,
                                                        const _Float16* __restrict__ zp,
                                                        float* __restrict__ off) {
    __shared__ unsigned short As[32 * 32];
    __shared__ unsigned short Bs[32 * 32];

    const int tid = threadIdx.x;
    const int lane = tid & 63;
    const int wave = tid >> 6;
    const int quad = lane >> 4;
    const int l15 = lane & 15;
    const int row0 = blockIdx.x * 32;
    const int tap = blockIdx.y;
    const int dt = (tap / 3 - 1) * RATIO;
    const int dn = (tap % 3 - 1) * RATIO;

    // staging: each thread owns one 16B chunk. waves 0/1 -> A rows 0..31,
    // waves 2/3 -> B rows 0..31. chunk cc: row m=cc>>2, k-chunk (cc&3)^(m&3).
    const int cc = tid & 127;
    const int m = cc >> 2;
    const int kq = (cc & 3) ^ (m & 3);
    const _Float16* gsrc;
    if (wave < 2) {
        const int r = row0 + m;
        const int b = r / (Tt * Nn);
        const int t = (r / Nn) % Tt;
        const int n = r % Nn;
        const int tt = t + dt, nn = n + dn;
        const bool ok = ((unsigned)tt < (unsigned)Tt) && ((unsigned)nn < (unsigned)Nn);
        const int sr = (b * Tt + tt) * Nn + nn;
        gsrc = ok ? (xh + (size_t)sr * Cc + kq * 8) : (zp + kq * 8);
    } else {
        gsrc = wh + ((size_t)tap * 32 + m) * Cc + kq * 8;
    }
    unsigned short* ldst = (wave < 2 ? As : Bs) + (wave & 1) * 512;  // 1024B/wave

    floatx4 acc = (floatx4){0.f, 0.f, 0.f, 0.f};
    const int m0 = (wave >> 1) * 16;
    const int n0 = (wave & 1) * 16;
    const int ma = m0 + l15;
    const int nb = n0 + l15;
    const int aoff = ma * 32 + ((quad ^ (ma & 3)) << 3);
    const int boff = nb * 32 + ((quad ^ (nb & 3)) << 3);

    for (int kt = 0; kt < Cc; kt += 32) {
        __builtin_amdgcn_global_load_lds((guint*)(const void*)(gsrc + kt),
                                         (luint*)(void*)ldst, 16, 0, 0);
        __syncthreads();
        half8 av = __builtin_bit_cast(half8, *(const short8*)&As[aoff]);
        half8 bv = __builtin_bit_cast(half8, *(const short8*)&Bs[boff]);
        acc = __builtin_amdgcn_mfma_f32_16x16x32_f16(av, bv, acc, 0, 0, 0);
        __syncthreads();
    }

    const int o = n0 + l15;
    if (o < 18) {
        const int grow = row0 + m0 + quad * 4;
#pragma unroll
        for (int r = 0; r < 4; ++r)
            atomicAdd(&off[(size_t)(grow + r) * 18 + o], acc[r]);
    }
}

// ---------------------------------------------------------------------------
// Kernel 2: deformable bilinear gather.
// One block per row (b,t,n); 256 threads over channels (4 each).
// RATIO==1: ftsum[row][c]  = sum_k ft_infer
// RATIO==2: Ab[row][c]     = bf16((ftsum + sum_k)/18); mad[row][k][c] = ft_infer
// ---------------------------------------------------------------------------
template <int RATIO, bool FINAL>
__global__ __launch_bounds__(256) void gather_kernel(const float* __restrict__ pf,
                                                     const float* __restrict__ off,
                                                     float* __restrict__ ftsum,
                                                     unsigned short* __restrict__ Ab,
                                                     float* __restrict__ mad) {
    const int row = blockIdx.x;
    const int b = row / (Tt * Nn);
    const int t = (row / Nn) % Tt;
    const int n = row % Nn;
    const int tid = threadIdx.x;

    __shared__ float so[18];
    if (tid < 18) so[tid] = off[(size_t)row * 18 + tid];
    __syncthreads();

    const float tmax = (float)(Tt + 2 * RATIO - 1);
    const float nmax = (float)(Nn + 2 * RATIO - 1);

    float acc[4] = {0.f, 0.f, 0.f, 0.f};

#pragma unroll
    for (int k = 0; k < 9; ++k) {
        const float gt = (float)((k / 3 - 1) * RATIO);
        const float gn = (float)((k % 3 - 1) * RATIO);
        const float pos_t = (float)(t + RATIO) + gt + so[k];
        const float pos_n = (float)(n + RATIO) + gn + so[9 + k];

        const float fl_t = floorf(pos_t), fl_n = floorf(pos_n);
        const float l_t = fminf(fmaxf(fl_t, 0.f), tmax);
        const float r_t = fminf(fmaxf(fl_t + 1.f, 0.f), tmax);
        const float l_n = fminf(fmaxf(fl_n, 0.f), nmax);
        const float r_n = fminf(fmaxf(fl_n + 1.f, 0.f), nmax);
        const float pt_ = fminf(fmaxf(pos_t, 0.f), tmax);
        const float pn_ = fminf(fmaxf(pos_n, 0.f), nmax);

        const float wtl = 1.f - fabsf(pt_ - l_t);
        const float wtr = 1.f - fabsf(pt_ - r_t);
        const float wnl = 1.f - fabsf(pn_ - l_n);
        const float wnr = 1.f - fabsf(pn_ - r_n);

        const float clt = wtl * wnl;   // (l_t, l_n)
        const float crb = wtr * wnr;   // (r_t, r_n)
        const float clb = wtr * wnl;   // (r_t, l_n)
        const float crt = wtl * wnr;   // (l_t, r_n)

        const int ilt = (int)l_t - RATIO, irt = (int)r_t - RATIO;
        const int iln = (int)l_n - RATIO, irn = (int)r_n - RATIO;
        const bool vtl = (unsigned)ilt < (unsigned)Tt;
        const bool vtr = (unsigned)irt < (unsigned)Tt;
        const bool vnl = (unsigned)iln < (unsigned)Nn;
        const bool vnr = (unsigned)irn < (unsigned)Nn;

        const size_t base_b = (size_t)b * Tt * Nn * Cc;
        const size_t o_lt = base_b + ((size_t)ilt * Nn + iln) * Cc;
        const size_t o_rb = base_b + ((size_t)irt * Nn + irn) * Cc;
        const size_t o_lb = base_b + ((size_t)irt * Nn + iln) * Cc;
        const size_t o_rt = base_b + ((size_t)ilt * Nn + irn) * Cc;
        const bool g_lt = vtl && vnl, g_rb = vtr && vnr;
        const bool g_lb = vtr && vnl, g_rt = vtl && vnr;

#pragma unroll
        for (int ci = 0; ci < 4; ++ci) {
            const int c = tid + ci * 256;
            const float s_lt = g_lt ? pf[o_lt + c] : 0.f;
            const float s_rb = g_rb ? pf[o_rb + c] : 0.f;
            const float s_lb = g_lb ? pf[o_lb + c] : 0.f;
            const float s_rt = g_rt ? pf[o_rt + c] : 0.f;
            const float val = clt * s_lt + crb * s_rb + clb * s_lb + crt * s_rt;
            acc[ci] += val;
            if (FINAL) mad[((size_t)row * 9 + k) * Cc + c] = val;
        }
    }

#pragma unroll
    for (int ci = 0; ci < 4; ++ci) {
        const int c = tid + ci * 256;
        if (FINAL) {
            const float f = (ftsum[(size_t)row * Cc + c] + acc[ci]) * (1.f / 18.f);
            Ab[(size_t)row * Cc + c] = f2bf(f);
        } else {
            ftsum[(size_t)row * Cc + c] = acc[ci];
        }
    }
}

// ---------------------------------------------------------------------------
// Kernel 3: bf16 MFMA GEMM  C[M][N] = A[M][K] * B[N][K]^T  (both K-major)
// 128x128 tile, BK=32, 4 waves each computing 64x64 (4x4 of 16x16x32 frags).
// ---------------------------------------------------------------------------
__global__ __launch_bounds__(256) void gemm_bt_kernel(const unsigned short* __restrict__ A,
                                                      const unsigned short* __restrict__ Bw,
                                                      float* __restrict__ C,
                                                      int M, int N, int K) {
    __shared__ unsigned short As[128 * 32];
    __shared__ unsigned short Bs[128 * 32];

    const int tid  = threadIdx.x;
    const int lane = tid & 63;
    const int wave = tid >> 6;
    const int quad = lane >> 4;
    const int l15  = lane & 15;
    const int row0 = blockIdx.x * 128;
    const int col0 = blockIdx.y * 128;
    const int wm = (wave >> 1) * 64;
    const int wn = (wave & 1) * 64;

    floatx4 acc[4][4];
#pragma unroll
    for (int i = 0; i < 4; ++i)
#pragma unroll
        for (int j = 0; j < 4; ++j) acc[i][j] = (floatx4){0.f, 0.f, 0.f, 0.f};

    const int cc0 = tid,      m0 = cc0 >> 2, kq0 = (cc0 & 3) ^ (m0 & 3);
    const int cc1 = tid + 256, m1 = cc1 >> 2, kq1 = (cc1 & 3) ^ (m1 & 3);
    const unsigned short* gA0 = A  + (size_t)(row0 + m0) * K + kq0 * 8;
    const unsigned short* gA1 = A  + (size_t)(row0 + m1) * K + kq1 * 8;
    const unsigned short* gB0 = Bw + (size_t)(col0 + m0) * K + kq0 * 8;
    const unsigned short* gB1 = Bw + (size_t)(col0 + m1) * K + kq1 * 8;
    unsigned short* lA0 = As + wave * 512;
    unsigned short* lA1 = As + 2048 + wave * 512;
    unsigned short* lB0 = Bs + wave * 512;
    unsigned short* lB1 = Bs + 2048 + wave * 512;

    for (int kt = 0; kt < K; kt += 32) {
        __builtin_amdgcn_global_load_lds((guint*)(const void*)(gA0 + kt), (luint*)(void*)lA0, 16, 0, 0);
        __builtin_amdgcn_global_load_lds((guint*)(const void*)(gA1 + kt), (luint*)(void*)lA1, 16, 0, 0);
        __builtin_amdgcn_global_load_lds((guint*)(const void*)(gB0 + kt), (luint*)(void*)lB0, 16, 0, 0);
        __builtin_amdgcn_global_load_lds((guint*)(const void*)(gB1 + kt), (luint*)(void*)lB1, 16, 0, 0);
        __syncthreads();

        short8 af[4], bf[4];
#pragma unroll
        for (int i = 0; i < 4; ++i) {
            const int m = wm + i * 16 + l15;
            af[i] = *(const short8*)&As[m * 32 + ((quad ^ (m & 3)) << 3)];
            const int n = wn + i * 16 + l15;
            bf[i] = *(const short8*)&Bs[n * 32 + ((quad ^ (n & 3)) << 3)];
        }
#pragma unroll
        for (int i = 0; i < 4; ++i)
#pragma unroll
            for (int j = 0; j < 4; ++j)
                acc[i][j] = __builtin_amdgcn_mfma_f32_16x16x32_bf16(af[i], bf[j], acc[i][j], 0, 0, 0);
        __syncthreads();
    }

#pragma unroll
    for (int i = 0; i < 4; ++i)
#pragma unroll
        for (int j = 0; j < 4; ++j)
#pragma unroll
            for (int r = 0; r < 4; ++r) {
                const int row = row0 + wm + i * 16 + quad * 4 + r;
                const int col = col0 + wn + j * 16 + l15;
                C[(size_t)row * N + col] = acc[i][j][r];
            }
}

// ---------------------------------------------------------------------------
extern "C" void kernel_launch(void* const* d_in, const int* in_sizes, int n_in,
                              void* d_out, int out_size, void* d_ws, size_t ws_size,
                              hipStream_t stream) {
    const float* pf = (const float*)d_in[0];   // [B,T,N,C]
    const float* Wh = (const float*)d_in[1];   // [C,C]
    const float* w1 = (const float*)d_in[2];   // [18,C,3,3]
    const float* b1 = (const float*)d_in[3];   // [18]
    const float* w2 = (const float*)d_in[4];
    const float* b2 = (const float*)d_in[5];

    float* dyn = (float*)d_out;                    // [ROWS][C]
    float* mad = dyn + (size_t)ROWS * Cc;          // [ROWS][9][C]

    // workspace layout (~24.5 MB)
    float* off1  = (float*)d_ws;                                  // ROWS*18
    float* off2  = off1 + (size_t)ROWS * 18;                      // ROWS*18
    float* ftsum = off2 + (size_t)ROWS * 18;                      // ROWS*C
    unsigned short* Ab = (unsigned short*)(ftsum + (size_t)ROWS * Cc);   // ROWS*C bf16
    unsigned short* Wb = Ab + (size_t)ROWS * Cc;                  // C*C bf16
    _Float16* xh  = (_Float16*)(Wb + (size_t)Cc * Cc);            // ROWS*C fp16
    _Float16* wh1 = xh + (size_t)ROWS * Cc;                       // 9*32*C fp16
    _Float16* wh2 = wh1 + (size_t)9 * 32 * Cc;                    // 9*32*C fp16
    _Float16* zp  = wh2 + (size_t)9 * 32 * Cc;                    // C fp16 zeros

    convw_kernel<<<(Cc * Cc) / (256 * 4), 256, 0, stream>>>(Wh, Wb);
    convxh_kernel<<<(ROWS * Cc) / (256 * 4), 256, 0, stream>>>(pf, xh);
    convwh_kernel<<<(9 * 32 * Cc) / 256, 256, 0, stream>>>(w1, w2, wh1, wh2);
    init_kernel<<<(ROWS * 18 + 255) / 256, 256, 0, stream>>>(b1, b2, off1, off2, zp);

    offs_mfma_kernel<1><<<dim3(ROWS / 32, 9), 256, 0, stream>>>(xh, wh1, zp, off1);
    offs_mfma_kernel<2><<<dim3(ROWS / 32, 9), 256, 0, stream>>>(xh, wh2, zp, off2);

    gather_kernel<1, false><<<ROWS, 256, 0, stream>>>(pf, off1, ftsum, nullptr, nullptr);
    gather_kernel<2, true><<<ROWS, 256, 0, stream>>>(pf, off2, ftsum, Ab, mad);
    gemm_bt_kernel<<<dim3(20, 8), 256, 0, stream>>>(Ab, Wb, dyn, ROWS, Cc, Cc);
}

// Round 3
// 226.264 us; speedup vs baseline: 1.5518x; 1.0852x over previous
//
#include <hip/hip_runtime.h>
#include <hip/hip_bf16.h>

// Problem constants (from setup_inputs)
#define Bb 8
#define Tt 20
#define Nn 16
#define Cc 1024
#define ROWS (Bb * Tt * Nn)   // 2560
#define K2 9

typedef __attribute__((ext_vector_type(8))) short short8;
typedef __attribute__((ext_vector_type(8))) _Float16 half8;
typedef __attribute__((ext_vector_type(4))) _Float16 half4;
typedef __attribute__((ext_vector_type(4))) float floatx4;
typedef __attribute__((address_space(1))) const unsigned int guint;
typedef __attribute__((address_space(3))) unsigned int luint;

static __device__ __forceinline__ unsigned short f2bf(float f) {
    unsigned int u = __builtin_bit_cast(unsigned int, f);
    unsigned int lsb = (u >> 16) & 1u;
    u += 0x7fffu + lsb;                 // round-to-nearest-even
    return (unsigned short)(u >> 16);
}

// ---------------------------------------------------------------------------
// Kernel 0 (prep): one kernel, four block-segments.
//   [0,1024)      : W_hidden fp32 -> bf16 (4 elem/thread)
//   [1024,3584)   : x fp32 -> fp16        (4 elem/thread)
//   [3584,4736)   : conv weights -> [tap][32][C] fp16 (o zero-padded to 32)
//   [4736,4917)   : off1/off2 bias init + fp16 zero page
// ---------------------------------------------------------------------------
#define SEG0 1024
#define SEG1 3584
#define SEG2 4736
#define SEG3 4917

__global__ __launch_bounds__(256) void prep_kernel(const float* __restrict__ pf,
                                                   const float* __restrict__ Wh,
                                                   const float* __restrict__ w1,
                                                   const float* __restrict__ b1,
                                                   const float* __restrict__ w2,
                                                   const float* __restrict__ b2,
                                                   unsigned short* __restrict__ Wb,
                                                   _Float16* __restrict__ xh,
                                                   _Float16* __restrict__ wh1,
                                                   _Float16* __restrict__ wh2,
                                                   float* __restrict__ off1,
                                                   float* __restrict__ off2,
                                                   _Float16* __restrict__ zp) {
    const int bid = blockIdx.x;
    const int tid = threadIdx.x;
    if (bid < SEG0) {
        int idx = (bid * 256 + tid) * 4;
        float4 v = *(const float4*)(Wh + idx);
        ushort4 o;
        o.x = f2bf(v.x); o.y = f2bf(v.y); o.z = f2bf(v.z); o.w = f2bf(v.w);
        *(ushort4*)(Wb + idx) = o;
    } else if (bid < SEG1) {
        int idx = ((bid - SEG0) * 256 + tid) * 4;
        float4 v = *(const float4*)(pf + idx);
        half4 o;
        o.x = (_Float16)v.x; o.y = (_Float16)v.y; o.z = (_Float16)v.z; o.w = (_Float16)v.w;
        *(half4*)(xh + idx) = o;
    } else if (bid < SEG2) {
        int idx = (bid - SEG1) * 256 + tid;     // 9*32*1024 total
        int c = idx & 1023;
        int o = (idx >> 10) & 31;
        int tap = idx >> 15;
        float v1 = 0.f, v2 = 0.f;
        if (o < 18) {
            size_t src = ((size_t)o * Cc + c) * 9 + tap;
            v1 = w1[src]; v2 = w2[src];
        }
        wh1[idx] = (_Float16)v1;
        wh2[idx] = (_Float16)v2;
    } else {
        int idx = (bid - SEG2) * 256 + tid;
        if (idx < Cc) zp[idx] = (_Float16)0.f;
        if (idx < ROWS * 18) {
            int o = idx % 18;
            off1[idx] = b1[o];
            off2[idx] = b2[o];
        }
    }
}

// ---------------------------------------------------------------------------
// Kernel 1: offset conv as split-tap MFMA GEMM, both ratios in one launch.
// Grid (80 M-tiles of 32 rows, 9 taps, 2 ratios). 4 waves; BK=64 (two 32-k
// tiles per barrier). A = shifted x rows (zero page OOB), B = wh[tap].
// fp32 atomicAdd into bias-initialized off.
// ---------------------------------------------------------------------------
__global__ __launch_bounds__(256) void offs_mfma_kernel(const _Float16* __restrict__ xh,
                                                        const _Float16* __restrict__ wh1,
                                                        const _Float16* __restrict__ wh2,
                                                        const _Float16* __restrict__ zp,
                                                        float* __restrict__ off1,
                                                        float* __restrict__ off2) {
    __shared__ unsigned short As[32 * 64];
    __shared__ unsigned short Bs[32 * 64];

    const int tid = threadIdx.x;
    const int lane = tid & 63;
    const int wave = tid >> 6;
    const int quad = lane >> 4;
    const int l15 = lane & 15;
    const int row0 = blockIdx.x * 32;
    const int tap = blockIdx.y;
    const int ratio = blockIdx.z + 1;
    const _Float16* __restrict__ wh = blockIdx.z ? wh2 : wh1;
    float* __restrict__ off = blockIdx.z ? off2 : off1;
    const int dt = (tap / 3 - 1) * ratio;
    const int dn = (tap % 3 - 1) * ratio;

    // staging: 32 rows x 8 k-chunks (16B each) per matrix; waves 0/1 -> A,
    // waves 2/3 -> B. Each thread stages 2 chunks: idx and idx+128.
    // chunk cc: row m=cc>>3, stored pos p=cc&7, global k-chunk p^(m&7).
    const int idx = tid & 127;
    const int p = idx & 7;
    const int m0 = idx >> 3;           // 0..15
    const int m1 = m0 + 16;            // 16..31
    const int kq0 = p ^ (m0 & 7);
    const int kq1 = p ^ (m1 & 7);

    const _Float16 *gsrc0, *gsrc1;
    if (wave < 2) {
        const int b = row0 / (Tt * Nn);        // 32 rows never cross a batch
        const int t0 = (row0 / Nn) % Tt;
        auto arow = [&](int m) -> const _Float16* {
            const int r = row0 + m;
            const int t = t0 + (m >> 4);       // rows row0..row0+31 span 2 t's
            const int n = r % Nn;
            const int tt = t + dt, nn = n + dn;
            const bool ok = ((unsigned)tt < (unsigned)Tt) && ((unsigned)nn < (unsigned)Nn);
            return ok ? xh + (size_t)((b * Tt + tt) * Nn + nn) * Cc : zp;
        };
        gsrc0 = arow(m0) + kq0 * 8;
        gsrc1 = arow(m1) + kq1 * 8;
    } else {
        gsrc0 = wh + ((size_t)tap * 32 + m0) * Cc + kq0 * 8;
        gsrc1 = wh + ((size_t)tap * 32 + m1) * Cc + kq1 * 8;
    }
    unsigned short* base = (wave < 2) ? As : Bs;
    unsigned short* lds0 = base + (wave & 1) * 512;          // chunk idx
    unsigned short* lds1 = base + 1024 + (wave & 1) * 512;   // chunk idx+128

    floatx4 acc = (floatx4){0.f, 0.f, 0.f, 0.f};
    const int ma = (wave >> 1) * 16 + l15;
    const int nb = (wave & 1) * 16 + l15;

    for (int kt = 0; kt < Cc; kt += 64) {
        __builtin_amdgcn_global_load_lds((guint*)(const void*)(gsrc0 + kt),
                                         (luint*)(void*)lds0, 16, 0, 0);
        __builtin_amdgcn_global_load_lds((guint*)(const void*)(gsrc1 + kt),
                                         (luint*)(void*)lds1, 16, 0, 0);
        __syncthreads();
#pragma unroll
        for (int kt2 = 0; kt2 < 2; ++kt2) {
            const int ca = (kt2 * 4 + quad) ^ (ma & 7);
            const int cb = (kt2 * 4 + quad) ^ (nb & 7);
            half8 av = __builtin_bit_cast(half8, *(const short8*)&As[ma * 64 + ca * 8]);
            half8 bv = __builtin_bit_cast(half8, *(const short8*)&Bs[nb * 64 + cb * 8]);
            acc = __builtin_amdgcn_mfma_f32_16x16x32_f16(av, bv, acc, 0, 0, 0);
        }
        __syncthreads();
    }

    const int o = (wave & 1) * 16 + l15;
    if (o < 18) {
        const int grow = row0 + (wave >> 1) * 16 + quad * 4;
#pragma unroll
        for (int r = 0; r < 4; ++r)
            atomicAdd(&off[(size_t)(grow + r) * 18 + o], acc[r]);
    }
}

// ---------------------------------------------------------------------------
// Kernel 2: fused deformable bilinear gather, both ratios.
// One block per row (b,t,n); 256 threads over channels (4 each).
//   mad[row][k][c] = ft_infer(ratio2);  Ab[row][c] = bf16(sum/18)
// ---------------------------------------------------------------------------
template <int RATIO, bool FINAL>
static __device__ __forceinline__ void gather_accum(const float* __restrict__ pf,
                                                    const float* so, int b, int t, int n,
                                                    int tid, size_t row, float* acc,
                                                    float* __restrict__ mad) {
    const float tmax = (float)(Tt + 2 * RATIO - 1);
    const float nmax = (float)(Nn + 2 * RATIO - 1);
#pragma unroll
    for (int k = 0; k < 9; ++k) {
        const float gt = (float)((k / 3 - 1) * RATIO);
        const float gn = (float)((k % 3 - 1) * RATIO);
        const float pos_t = (float)(t + RATIO) + gt + so[k];
        const float pos_n = (float)(n + RATIO) + gn + so[9 + k];

        const float fl_t = floorf(pos_t), fl_n = floorf(pos_n);
        const float l_t = fminf(fmaxf(fl_t, 0.f), tmax);
        const float r_t = fminf(fmaxf(fl_t + 1.f, 0.f), tmax);
        const float l_n = fminf(fmaxf(fl_n, 0.f), nmax);
        const float r_n = fminf(fmaxf(fl_n + 1.f, 0.f), nmax);
        const float pt_ = fminf(fmaxf(pos_t, 0.f), tmax);
        const float pn_ = fminf(fmaxf(pos_n, 0.f), nmax);

        const float wtl = 1.f - fabsf(pt_ - l_t);
        const float wtr = 1.f - fabsf(pt_ - r_t);
        const float wnl = 1.f - fabsf(pn_ - l_n);
        const float wnr = 1.f - fabsf(pn_ - r_n);

        const float clt = wtl * wnl;   // (l_t, l_n)
        const float crb = wtr * wnr;   // (r_t, r_n)
        const float clb = wtr * wnl;   // (r_t, l_n)
        const float crt = wtl * wnr;   // (l_t, r_n)

        const int ilt = (int)l_t - RATIO, irt = (int)r_t - RATIO;
        const int iln = (int)l_n - RATIO, irn = (int)r_n - RATIO;
        const bool vtl = (unsigned)ilt < (unsigned)Tt;
        const bool vtr = (unsigned)irt < (unsigned)Tt;
        const bool vnl = (unsigned)iln < (unsigned)Nn;
        const bool vnr = (unsigned)irn < (unsigned)Nn;

        const size_t base_b = (size_t)b * Tt * Nn * Cc;
        const size_t o_lt = base_b + ((size_t)ilt * Nn + iln) * Cc;
        const size_t o_rb = base_b + ((size_t)irt * Nn + irn) * Cc;
        const size_t o_lb = base_b + ((size_t)irt * Nn + iln) * Cc;
        const size_t o_rt = base_b + ((size_t)ilt * Nn + irn) * Cc;
        const bool g_lt = vtl && vnl, g_rb = vtr && vnr;
        const bool g_lb = vtr && vnl, g_rt = vtl && vnr;

#pragma unroll
        for (int ci = 0; ci < 4; ++ci) {
            const int c = tid + ci * 256;
            const float s_lt = g_lt ? pf[o_lt + c] : 0.f;
            const float s_rb = g_rb ? pf[o_rb + c] : 0.f;
            const float s_lb = g_lb ? pf[o_lb + c] : 0.f;
            const float s_rt = g_rt ? pf[o_rt + c] : 0.f;
            const float val = clt * s_lt + crb * s_rb + clb * s_lb + crt * s_rt;
            acc[ci] += val;
            if (FINAL) mad[(row * 9 + k) * Cc + c] = val;
        }
    }
}

__global__ __launch_bounds__(256) void gather_kernel(const float* __restrict__ pf,
                                                     const float* __restrict__ off1,
                                                     const float* __restrict__ off2,
                                                     unsigned short* __restrict__ Ab,
                                                     float* __restrict__ mad) {
    const int row = blockIdx.x;
    const int b = row / (Tt * Nn);
    const int t = (row / Nn) % Tt;
    const int n = row % Nn;
    const int tid = threadIdx.x;

    __shared__ float so[36];
    if (tid < 18) so[tid] = off1[(size_t)row * 18 + tid];
    else if (tid < 36) so[tid] = off2[(size_t)row * 18 + tid - 18];
    __syncthreads();

    float acc[4] = {0.f, 0.f, 0.f, 0.f};
    gather_accum<1, false>(pf, so, b, t, n, tid, row, acc, nullptr);
    gather_accum<2, true>(pf, so + 18, b, t, n, tid, row, acc, mad);

#pragma unroll
    for (int ci = 0; ci < 4; ++ci) {
        const int c = tid + ci * 256;
        Ab[(size_t)row * Cc + c] = f2bf(acc[ci] * (1.f / 18.f));
    }
}

// ---------------------------------------------------------------------------
// Kernel 3: bf16 MFMA GEMM  C[M][N] = A[M][K] * B[N][K]^T, 64x64 tiles for
// occupancy (grid 40x16 = 640 blocks). 4 waves, each 32x32 (2x2 frags).
// ---------------------------------------------------------------------------
__global__ __launch_bounds__(256) void gemm_bt_kernel(const unsigned short* __restrict__ A,
                                                      const unsigned short* __restrict__ Bw,
                                                      float* __restrict__ C,
                                                      int M, int N, int K) {
    __shared__ unsigned short As[64 * 32];
    __shared__ unsigned short Bs[64 * 32];

    const int tid  = threadIdx.x;
    const int lane = tid & 63;
    const int wave = tid >> 6;
    const int quad = lane >> 4;
    const int l15  = lane & 15;
    const int row0 = blockIdx.x * 64;
    const int col0 = blockIdx.y * 64;
    const int wm = (wave >> 1) * 32;
    const int wn = (wave & 1) * 32;

    floatx4 acc[2][2];
#pragma unroll
    for (int i = 0; i < 2; ++i)
#pragma unroll
        for (int j = 0; j < 2; ++j) acc[i][j] = (floatx4){0.f, 0.f, 0.f, 0.f};

    // 64 rows x 4 chunks per matrix; thread stages A chunk tid and B chunk tid
    const int m = tid >> 2, kq = (tid & 3) ^ (m & 3);
    const unsigned short* gA = A  + (size_t)(row0 + m) * K + kq * 8;
    const unsigned short* gB = Bw + (size_t)(col0 + m) * K + kq * 8;
    unsigned short* lA = As + wave * 512;
    unsigned short* lB = Bs + wave * 512;

    for (int kt = 0; kt < K; kt += 32) {
        __builtin_amdgcn_global_load_lds((guint*)(const void*)(gA + kt), (luint*)(void*)lA, 16, 0, 0);
        __builtin_amdgcn_global_load_lds((guint*)(const void*)(gB + kt), (luint*)(void*)lB, 16, 0, 0);
        __syncthreads();

        short8 af[2], bf[2];
#pragma unroll
        for (int i = 0; i < 2; ++i) {
            const int mm = wm + i * 16 + l15;
            af[i] = *(const short8*)&As[mm * 32 + ((quad ^ (mm & 3)) << 3)];
            const int nn = wn + i * 16 + l15;
            bf[i] = *(const short8*)&Bs[nn * 32 + ((quad ^ (nn & 3)) << 3)];
        }
#pragma unroll
        for (int i = 0; i < 2; ++i)
#pragma unroll
            for (int j = 0; j < 2; ++j)
                acc[i][j] = __builtin_amdgcn_mfma_f32_16x16x32_bf16(af[i], bf[j], acc[i][j], 0, 0, 0);
        __syncthreads();
    }

#pragma unroll
    for (int i = 0; i < 2; ++i)
#pragma unroll
        for (int j = 0; j < 2; ++j)
#pragma unroll
            for (int r = 0; r < 4; ++r) {
                const int row = row0 + wm + i * 16 + quad * 4 + r;
                const int col = col0 + wn + j * 16 + l15;
                C[(size_t)row * N + col] = acc[i][j][r];
            }
}

// ---------------------------------------------------------------------------
extern "C" void kernel_launch(void* const* d_in, const int* in_sizes, int n_in,
                              void* d_out, int out_size, void* d_ws, size_t ws_size,
                              hipStream_t stream) {
    const float* pf = (const float*)d_in[0];   // [B,T,N,C]
    const float* Wh = (const float*)d_in[1];   // [C,C]
    const float* w1 = (const float*)d_in[2];   // [18,C,3,3]
    const float* b1 = (const float*)d_in[3];   // [18]
    const float* w2 = (const float*)d_in[4];
    const float* b2 = (const float*)d_in[5];

    float* dyn = (float*)d_out;                    // [ROWS][C]
    float* mad = dyn + (size_t)ROWS * Cc;          // [ROWS][9][C]

    // workspace layout
    float* off1  = (float*)d_ws;                                  // ROWS*18
    float* off2  = off1 + (size_t)ROWS * 18;                      // ROWS*18
    unsigned short* Ab = (unsigned short*)(off2 + (size_t)ROWS * 18);    // ROWS*C bf16
    unsigned short* Wb = Ab + (size_t)ROWS * Cc;                  // C*C bf16
    _Float16* xh  = (_Float16*)(Wb + (size_t)Cc * Cc);            // ROWS*C fp16
    _Float16* wh1 = xh + (size_t)ROWS * Cc;                       // 9*32*C fp16
    _Float16* wh2 = wh1 + (size_t)9 * 32 * Cc;                    // 9*32*C fp16
    _Float16* zp  = wh2 + (size_t)9 * 32 * Cc;                    // C fp16 zeros

    prep_kernel<<<SEG3, 256, 0, stream>>>(pf, Wh, w1, b1, w2, b2,
                                          Wb, xh, wh1, wh2, off1, off2, zp);
    offs_mfma_kernel<<<dim3(ROWS / 32, 9, 2), 256, 0, stream>>>(xh, wh1, wh2, zp, off1, off2);
    gather_kernel<<<ROWS, 256, 0, stream>>>(pf, off1, off2, Ab, mad);
    gemm_bt_kernel<<<dim3(40, 16), 256, 0, stream>>>(Ab, Wb, dyn, ROWS, Cc, Cc);
}

// Round 4
// 180.938 us; speedup vs baseline: 1.9406x; 1.2505x over previous
//
#include <hip/hip_runtime.h>
#include <hip/hip_bf16.h>

// Problem constants (from setup_inputs)
#define Bb 8
#define Tt 20
#define Nn 16
#define Cc 1024
#define ROWS (Bb * Tt * Nn)   // 2560
#define K2 9

typedef __attribute__((ext_vector_type(8))) short short8;
typedef __attribute__((ext_vector_type(8))) _Float16 half8;
typedef __attribute__((ext_vector_type(4))) _Float16 half4;
typedef __attribute__((ext_vector_type(4))) float floatx4;
typedef __attribute__((address_space(1))) const unsigned int guint;
typedef __attribute__((address_space(3))) unsigned int luint;

static __device__ __forceinline__ unsigned short f2bf(float f) {
    unsigned int u = __builtin_bit_cast(unsigned int, f);
    unsigned int lsb = (u >> 16) & 1u;
    u += 0x7fffu + lsb;                 // round-to-nearest-even
    return (unsigned short)(u >> 16);
}

// ---------------------------------------------------------------------------
// Kernel 0 (prep): one kernel, four block-segments.
//   [0,1024)      : W_hidden fp32 -> bf16 (4 elem/thread)
//   [1024,3584)   : x fp32 -> fp16        (4 elem/thread)
//   [3584,4736)   : conv weights -> [tap][32][C] fp16 (o zero-padded to 32)
//   [4736,4917)   : off1/off2 bias init + fp16 zero page
// ---------------------------------------------------------------------------
#define SEG0 1024
#define SEG1 3584
#define SEG2 4736
#define SEG3 4917

__global__ __launch_bounds__(256) void prep_kernel(const float* __restrict__ pf,
                                                   const float* __restrict__ Wh,
                                                   const float* __restrict__ w1,
                                                   const float* __restrict__ b1,
                                                   const float* __restrict__ w2,
                                                   const float* __restrict__ b2,
                                                   unsigned short* __restrict__ Wb,
                                                   _Float16* __restrict__ xh,
                                                   _Float16* __restrict__ wh1,
                                                   _Float16* __restrict__ wh2,
                                                   float* __restrict__ off1,
                                                   float* __restrict__ off2,
                                                   _Float16* __restrict__ zp) {
    const int bid = blockIdx.x;
    const int tid = threadIdx.x;
    if (bid < SEG0) {
        int idx = (bid * 256 + tid) * 4;
        float4 v = *(const float4*)(Wh + idx);
        ushort4 o;
        o.x = f2bf(v.x); o.y = f2bf(v.y); o.z = f2bf(v.z); o.w = f2bf(v.w);
        *(ushort4*)(Wb + idx) = o;
    } else if (bid < SEG1) {
        int idx = ((bid - SEG0) * 256 + tid) * 4;
        float4 v = *(const float4*)(pf + idx);
        half4 o;
        o.x = (_Float16)v.x; o.y = (_Float16)v.y; o.z = (_Float16)v.z; o.w = (_Float16)v.w;
        *(half4*)(xh + idx) = o;
    } else if (bid < SEG2) {
        int idx = (bid - SEG1) * 256 + tid;     // 9*32*1024 total
        int c = idx & 1023;
        int o = (idx >> 10) & 31;
        int tap = idx >> 15;
        float v1 = 0.f, v2 = 0.f;
        if (o < 18) {
            size_t src = ((size_t)o * Cc + c) * 9 + tap;
            v1 = w1[src]; v2 = w2[src];
        }
        wh1[idx] = (_Float16)v1;
        wh2[idx] = (_Float16)v2;
    } else {
        int idx = (bid - SEG2) * 256 + tid;
        if (idx < Cc) zp[idx] = (_Float16)0.f;
        if (idx < ROWS * 18) {
            int o = idx % 18;
            off1[idx] = b1[o];
            off2[idx] = b2[o];
        }
    }
}

// ---------------------------------------------------------------------------
// Kernel 1: offset conv as split-tap MFMA GEMM, both ratios in one launch.
// Grid (80 M-tiles of 32 rows, 9 taps, 2 ratios). 4 waves; BK=64.
// fp32 atomicAdd into bias-initialized off.
// ---------------------------------------------------------------------------
__global__ __launch_bounds__(256) void offs_mfma_kernel(const _Float16* __restrict__ xh,
                                                        const _Float16* __restrict__ wh1,
                                                        const _Float16* __restrict__ wh2,
                                                        const _Float16* __restrict__ zp,
                                                        float* __restrict__ off1,
                                                        float* __restrict__ off2) {
    __shared__ unsigned short As[32 * 64];
    __shared__ unsigned short Bs[32 * 64];

    const int tid = threadIdx.x;
    const int lane = tid & 63;
    const int wave = tid >> 6;
    const int quad = lane >> 4;
    const int l15 = lane & 15;
    const int row0 = blockIdx.x * 32;
    const int tap = blockIdx.y;
    const int ratio = blockIdx.z + 1;
    const _Float16* __restrict__ wh = blockIdx.z ? wh2 : wh1;
    float* __restrict__ off = blockIdx.z ? off2 : off1;
    const int dt = (tap / 3 - 1) * ratio;
    const int dn = (tap % 3 - 1) * ratio;

    // staging: 32 rows x 8 k-chunks (16B) per matrix; waves 0/1 -> A,
    // waves 2/3 -> B. chunk: row m, stored pos p, global k-chunk p^(m&7).
    const int idx = tid & 127;
    const int p = idx & 7;
    const int m0 = idx >> 3;           // 0..15
    const int m1 = m0 + 16;            // 16..31
    const int kq0 = p ^ (m0 & 7);
    const int kq1 = p ^ (m1 & 7);

    const _Float16 *gsrc0, *gsrc1;
    if (wave < 2) {
        const int b = row0 / (Tt * Nn);        // 32 rows never cross a batch
        const int t0 = (row0 / Nn) % Tt;
        auto arow = [&](int m) -> const _Float16* {
            const int r = row0 + m;
            const int t = t0 + (m >> 4);       // rows row0..row0+31 span 2 t's
            const int n = r % Nn;
            const int tt = t + dt, nn = n + dn;
            const bool ok = ((unsigned)tt < (unsigned)Tt) && ((unsigned)nn < (unsigned)Nn);
            return ok ? xh + (size_t)((b * Tt + tt) * Nn + nn) * Cc : zp;
        };
        gsrc0 = arow(m0) + kq0 * 8;
        gsrc1 = arow(m1) + kq1 * 8;
    } else {
        gsrc0 = wh + ((size_t)tap * 32 + m0) * Cc + kq0 * 8;
        gsrc1 = wh + ((size_t)tap * 32 + m1) * Cc + kq1 * 8;
    }
    unsigned short* base = (wave < 2) ? As : Bs;
    unsigned short* lds0 = base + (wave & 1) * 512;          // chunk idx
    unsigned short* lds1 = base + 1024 + (wave & 1) * 512;   // chunk idx+128

    floatx4 acc = (floatx4){0.f, 0.f, 0.f, 0.f};
    const int ma = (wave >> 1) * 16 + l15;
    const int nb = (wave & 1) * 16 + l15;

    for (int kt = 0; kt < Cc; kt += 64) {
        __builtin_amdgcn_global_load_lds((guint*)(const void*)(gsrc0 + kt),
                                         (luint*)(void*)lds0, 16, 0, 0);
        __builtin_amdgcn_global_load_lds((guint*)(const void*)(gsrc1 + kt),
                                         (luint*)(void*)lds1, 16, 0, 0);
        __syncthreads();
#pragma unroll
        for (int kt2 = 0; kt2 < 2; ++kt2) {
            const int ca = (kt2 * 4 + quad) ^ (ma & 7);
            const int cb = (kt2 * 4 + quad) ^ (nb & 7);
            half8 av = __builtin_bit_cast(half8, *(const short8*)&As[ma * 64 + ca * 8]);
            half8 bv = __builtin_bit_cast(half8, *(const short8*)&Bs[nb * 64 + cb * 8]);
            acc = __builtin_amdgcn_mfma_f32_16x16x32_f16(av, bv, acc, 0, 0, 0);
        }
        __syncthreads();
    }

    const int o = (wave & 1) * 16 + l15;
    if (o < 18) {
        const int grow = row0 + (wave >> 1) * 16 + quad * 4;
#pragma unroll
        for (int r = 0; r < 4; ++r)
            atomicAdd(&off[(size_t)(grow + r) * 18 + o], acc[r]);
    }
}

// ---------------------------------------------------------------------------
// Kernel 2: fused deformable bilinear gather, descriptor form.
// One block per row. Threads 0..17 build tap descriptors (4 coefs + 4 int
// element-offsets; invalid corner -> coef 0 & offset 0) in LDS; then all 256
// threads do 4 contiguous channels each with float4 loads.
//   descriptors 0..8  = ratio1 taps, 9..17 = ratio2 taps (mad source).
// ---------------------------------------------------------------------------
__global__ __launch_bounds__(256) void gather_kernel(const float* __restrict__ pf,
                                                     const float* __restrict__ off1,
                                                     const float* __restrict__ off2,
                                                     unsigned short* __restrict__ Ab,
                                                     float* __restrict__ mad) {
    const int row = blockIdx.x;
    const int b = row / (Tt * Nn);
    const int t = (row / Nn) % Tt;
    const int n = row % Nn;
    const int tid = threadIdx.x;

    __shared__ float4 scoef[18];
    __shared__ int4   soffs[18];

    if (tid < 18) {
        const int ratio = (tid < 9) ? 1 : 2;
        const int k = (tid < 9) ? tid : tid - 9;
        const float* offarr = (tid < 9) ? off1 : off2;
        const float ot = offarr[(size_t)row * 18 + k];
        const float on = offarr[(size_t)row * 18 + 9 + k];
        const float tmax = (float)(Tt + 2 * ratio - 1);
        const float nmax = (float)(Nn + 2 * ratio - 1);
        const float pos_t = (float)(t + ratio + (k / 3 - 1) * ratio) + ot;
        const float pos_n = (float)(n + ratio + (k % 3 - 1) * ratio) + on;

        const float fl_t = floorf(pos_t), fl_n = floorf(pos_n);
        const float l_t = fminf(fmaxf(fl_t, 0.f), tmax);
        const float r_t = fminf(fmaxf(fl_t + 1.f, 0.f), tmax);
        const float l_n = fminf(fmaxf(fl_n, 0.f), nmax);
        const float r_n = fminf(fmaxf(fl_n + 1.f, 0.f), nmax);
        const float pt_ = fminf(fmaxf(pos_t, 0.f), tmax);
        const float pn_ = fminf(fmaxf(pos_n, 0.f), nmax);

        const float wtl = 1.f - fabsf(pt_ - l_t);
        const float wtr = 1.f - fabsf(pt_ - r_t);
        const float wnl = 1.f - fabsf(pn_ - l_n);
        const float wnr = 1.f - fabsf(pn_ - r_n);

        const int ilt = (int)l_t - ratio, irt = (int)r_t - ratio;
        const int iln = (int)l_n - ratio, irn = (int)r_n - ratio;
        const bool vtl = (unsigned)ilt < (unsigned)Tt;
        const bool vtr = (unsigned)irt < (unsigned)Tt;
        const bool vnl = (unsigned)iln < (unsigned)Nn;
        const bool vnr = (unsigned)irn < (unsigned)Nn;

        const int bb = b * Tt;
        float4 cf;
        int4 of;
        const bool g0 = vtl && vnl, g1 = vtr && vnr, g2 = vtr && vnl, g3 = vtl && vnr;
        cf.x = g0 ? wtl * wnl : 0.f;
        cf.y = g1 ? wtr * wnr : 0.f;
        cf.z = g2 ? wtr * wnl : 0.f;
        cf.w = g3 ? wtl * wnr : 0.f;
        of.x = g0 ? ((bb + ilt) * Nn + iln) * Cc : 0;
        of.y = g1 ? ((bb + irt) * Nn + irn) * Cc : 0;
        of.z = g2 ? ((bb + irt) * Nn + iln) * Cc : 0;
        of.w = g3 ? ((bb + ilt) * Nn + irn) * Cc : 0;
        scoef[tid] = cf;
        soffs[tid] = of;
    }
    __syncthreads();

    const int c4 = tid * 4;
    float ax = 0.f, ay = 0.f, az = 0.f, aw = 0.f;

#pragma unroll
    for (int d = 0; d < 9; ++d) {
        const float4 cf = scoef[d];
        const int4 of = soffs[d];
        const float4 v0 = *(const float4*)(pf + of.x + c4);
        const float4 v1 = *(const float4*)(pf + of.y + c4);
        const float4 v2 = *(const float4*)(pf + of.z + c4);
        const float4 v3 = *(const float4*)(pf + of.w + c4);
        ax += cf.x * v0.x + cf.y * v1.x + cf.z * v2.x + cf.w * v3.x;
        ay += cf.x * v0.y + cf.y * v1.y + cf.z * v2.y + cf.w * v3.y;
        az += cf.x * v0.z + cf.y * v1.z + cf.z * v2.z + cf.w * v3.z;
        aw += cf.x * v0.w + cf.y * v1.w + cf.z * v2.w + cf.w * v3.w;
    }
#pragma unroll
    for (int d = 9; d < 18; ++d) {
        const float4 cf = scoef[d];
        const int4 of = soffs[d];
        const float4 v0 = *(const float4*)(pf + of.x + c4);
        const float4 v1 = *(const float4*)(pf + of.y + c4);
        const float4 v2 = *(const float4*)(pf + of.z + c4);
        const float4 v3 = *(const float4*)(pf + of.w + c4);
        float4 val;
        val.x = cf.x * v0.x + cf.y * v1.x + cf.z * v2.x + cf.w * v3.x;
        val.y = cf.x * v0.y + cf.y * v1.y + cf.z * v2.y + cf.w * v3.y;
        val.z = cf.x * v0.z + cf.y * v1.z + cf.z * v2.z + cf.w * v3.z;
        val.w = cf.x * v0.w + cf.y * v1.w + cf.z * v2.w + cf.w * v3.w;
        *(float4*)(mad + ((size_t)row * 9 + (d - 9)) * Cc + c4) = val;
        ax += val.x; ay += val.y; az += val.z; aw += val.w;
    }

    ushort4 o;
    o.x = f2bf(ax * (1.f / 18.f));
    o.y = f2bf(ay * (1.f / 18.f));
    o.z = f2bf(az * (1.f / 18.f));
    o.w = f2bf(aw * (1.f / 18.f));
    *(ushort4*)(Ab + (size_t)row * Cc + c4) = o;
}

// ---------------------------------------------------------------------------
// Kernel 3: bf16 MFMA GEMM  C[M][N] = A[M][K] * B[N][K]^T, 64x64 tiles
// (grid 40x16 = 640 blocks). 4 waves, each 32x32 (2x2 frags).
// ---------------------------------------------------------------------------
__global__ __launch_bounds__(256) void gemm_bt_kernel(const unsigned short* __restrict__ A,
                                                      const unsigned short* __restrict__ Bw,
                                                      float* __restrict__ C,
                                                      int M, int N, int K) {
    __shared__ unsigned short As[64 * 32];
    __shared__ unsigned short Bs[64 * 32];

    const int tid  = threadIdx.x;
    const int lane = tid & 63;
    const int wave = tid >> 6;
    const int quad = lane >> 4;
    const int l15  = lane & 15;
    const int row0 = blockIdx.x * 64;
    const int col0 = blockIdx.y * 64;
    const int wm = (wave >> 1) * 32;
    const int wn = (wave & 1) * 32;

    floatx4 acc[2][2];
#pragma unroll
    for (int i = 0; i < 2; ++i)
#pragma unroll
        for (int j = 0; j < 2; ++j) acc[i][j] = (floatx4){0.f, 0.f, 0.f, 0.f};

    const int m = tid >> 2, kq = (tid & 3) ^ (m & 3);
    const unsigned short* gA = A  + (size_t)(row0 + m) * K + kq * 8;
    const unsigned short* gB = Bw + (size_t)(col0 + m) * K + kq * 8;
    unsigned short* lA = As + wave * 512;
    unsigned short* lB = Bs + wave * 512;

    for (int kt = 0; kt < K; kt += 32) {
        __builtin_amdgcn_global_load_lds((guint*)(const void*)(gA + kt), (luint*)(void*)lA, 16, 0, 0);
        __builtin_amdgcn_global_load_lds((guint*)(const void*)(gB + kt), (luint*)(void*)lB, 16, 0, 0);
        __syncthreads();

        short8 af[2], bf[2];
#pragma unroll
        for (int i = 0; i < 2; ++i) {
            const int mm = wm + i * 16 + l15;
            af[i] = *(const short8*)&As[mm * 32 + ((quad ^ (mm & 3)) << 3)];
            const int nn = wn + i * 16 + l15;
            bf[i] = *(const short8*)&Bs[nn * 32 + ((quad ^ (nn & 3)) << 3)];
        }
#pragma unroll
        for (int i = 0; i < 2; ++i)
#pragma unroll
            for (int j = 0; j < 2; ++j)
                acc[i][j] = __builtin_amdgcn_mfma_f32_16x16x32_bf16(af[i], bf[j], acc[i][j], 0, 0, 0);
        __syncthreads();
    }

#pragma unroll
    for (int i = 0; i < 2; ++i)
#pragma unroll
        for (int j = 0; j < 2; ++j)
#pragma unroll
            for (int r = 0; r < 4; ++r) {
                const int row = row0 + wm + i * 16 + quad * 4 + r;
                const int col = col0 + wn + j * 16 + l15;
                C[(size_t)row * N + col] = acc[i][j][r];
            }
}

// ---------------------------------------------------------------------------
extern "C" void kernel_launch(void* const* d_in, const int* in_sizes, int n_in,
                              void* d_out, int out_size, void* d_ws, size_t ws_size,
                              hipStream_t stream) {
    const float* pf = (const float*)d_in[0];   // [B,T,N,C]
    const float* Wh = (const float*)d_in[1];   // [C,C]
    const float* w1 = (const float*)d_in[2];   // [18,C,3,3]
    const float* b1 = (const float*)d_in[3];   // [18]
    const float* w2 = (const float*)d_in[4];
    const float* b2 = (const float*)d_in[5];

    float* dyn = (float*)d_out;                    // [ROWS][C]
    float* mad = dyn + (size_t)ROWS * Cc;          // [ROWS][9][C]

    // workspace layout
    float* off1  = (float*)d_ws;                                  // ROWS*18
    float* off2  = off1 + (size_t)ROWS * 18;                      // ROWS*18
    unsigned short* Ab = (unsigned short*)(off2 + (size_t)ROWS * 18);    // ROWS*C bf16
    unsigned short* Wb = Ab + (size_t)ROWS * Cc;                  // C*C bf16
    _Float16* xh  = (_Float16*)(Wb + (size_t)Cc * Cc);            // ROWS*C fp16
    _Float16* wh1 = xh + (size_t)ROWS * Cc;                       // 9*32*C fp16
    _Float16* wh2 = wh1 + (size_t)9 * 32 * Cc;                    // 9*32*C fp16
    _Float16* zp  = wh2 + (size_t)9 * 32 * Cc;                    // C fp16 zeros

    prep_kernel<<<SEG3, 256, 0, stream>>>(pf, Wh, w1, b1, w2, b2,
                                          Wb, xh, wh1, wh2, off1, off2, zp);
    offs_mfma_kernel<<<dim3(ROWS / 32, 9, 2), 256, 0, stream>>>(xh, wh1, wh2, zp, off1, off2);
    gather_kernel<<<ROWS, 256, 0, stream>>>(pf, off1, off2, Ab, mad);
    gemm_bt_kernel<<<dim3(40, 16), 256, 0, stream>>>(Ab, Wb, dyn, ROWS, Cc, Cc);
}